// Round 9
// baseline (194.906 us; speedup 1.0000x reference)
//
#include <hip/hip_runtime.h>
#include <math.h>

#define HH 192
#define WW 320
#define DTOT 507.0f
#define KD 39      // 3 channels * 13 dy
#define NSPAN 5
#define NCHUNK 5
#define XS 64      // w-span per block
#define TV 64      // v-chunk per block
#define TX 76      // XS + 12 halo (w side, "i")
#define TU 80      // TV + 12 halo padded to 80 (v side, "j")
#define TUW 76     // valid stat columns
#define TIS 76     // Tc inner (i) stride
#define TD2 77     // diagonal step in dwords (TIS+1)
#define NPIX (HH*WW)

typedef float v2f __attribute__((ext_vector_type(2)));

// ---------------- prep: scale = fx * ||(r_extri @ inv(l_extri))[:3,3]|| ; optional key zero ----------------
__global__ void prep_kernel(const float* __restrict__ li, const float* __restrict__ le,
                            const float* __restrict__ re, float* __restrict__ sc,
                            unsigned long long* __restrict__ keys) {
    int t = blockIdx.x * blockDim.x + threadIdx.x;
    if (keys != nullptr && t < NPIX) keys[t] = 0ull;
    if (t == 0) {
        float a[4][4], inv[4][4];
        for (int i = 0; i < 4; ++i)
            for (int j = 0; j < 4; ++j) { a[i][j] = le[i*4+j]; inv[i][j] = (i == j) ? 1.0f : 0.0f; }
        for (int c = 0; c < 4; ++c) {
            int p = c; float mx = fabsf(a[c][c]);
            for (int r = c+1; r < 4; ++r) { float v = fabsf(a[r][c]); if (v > mx) { mx = v; p = r; } }
            if (p != c) for (int j = 0; j < 4; ++j) {
                float tq = a[c][j]; a[c][j] = a[p][j]; a[p][j] = tq;
                tq = inv[c][j]; inv[c][j] = inv[p][j]; inv[p][j] = tq;
            }
            float id = 1.0f / a[c][c];
            for (int j = 0; j < 4; ++j) { a[c][j] *= id; inv[c][j] *= id; }
            for (int r = 0; r < 4; ++r) if (r != c) {
                float f = a[r][c];
                for (int j = 0; j < 4; ++j) { a[r][j] -= f*a[c][j]; inv[r][j] -= f*inv[c][j]; }
            }
        }
        float rel[3];
        for (int i = 0; i < 3; ++i)
            rel[i] = re[i*4+0]*inv[0][3] + re[i*4+1]*inv[1][3] + re[i*4+2]*inv[2][3] + re[i*4+3]*inv[3][3];
        float baseline = sqrtf(rel[0]*rel[0] + rel[1]*rel[1] + rel[2]*rel[2]);
        sc[0] = li[0] * baseline;
    }
}

// ---------------- match: round-6 verified structure + staging-integrated column sums ----------------
// All-f32 numerator (bf16/MFMA abandoned: exact-argmax test; critical tie margin in
// (1e-6, 5e-3), bf16 noise 5e-3 flips a clipped-disp pixel — rounds 7/8 evidence).
// Staging: one thread per slab column (156 threads): 39 coalesced loads, in-register
// colL/colR1/colR2 in identical k-order (bit-exact vs round-6 colsum phase), column
// write to f32 slab. Deletes the colsum phase + one barrier (4 -> 3).
// Phase A: pk_fma 4x8 tiles (verified round 6). Tc[j][i] col-major stride 76
// (Phase-B lane-coeff 1 = conflict-free; diag step 77, read2-pairable).
__global__ __launch_bounds__(256) void match_kernel(
        const float* __restrict__ limg, const float* __restrict__ rimg,
        unsigned long long* __restrict__ sink, int mode) {
    __shared__ float Ls[KD][TX];        // left slab: 39 x 76 (304B rows, 16B-aligned)
    __shared__ float Rs[KD][TU];        // right slab: 39 x 80 (cols 76..79 staged, unused for stats)
    __shared__ float Tc[TU][TIS];       // column-dot tile, [j][i], stride 76
    __shared__ float colL[TX];
    __shared__ float colR1[TUW];
    __shared__ float colR2[TUW];
    __shared__ float smuR[TV];
    __shared__ float sivR[TV];
    __shared__ float redS[4][XS];
    __shared__ int   redV[4][XS];

    const int span = blockIdx.x;        // 0..4
    const int h    = blockIdx.y;        // 0..191
    const int ch   = blockIdx.z;        // 0..4
    const int wlo  = span * XS;
    const int ulo  = ch * TV;
    const int tid  = threadIdx.x;
    const int lane = tid & 63;
    const int wave = tid >> 6;

    // ---- stage: column-per-thread, f32 slab write + in-register column sums ----
    if (tid < TX) {
        const int m  = tid;
        const int xg = wlo - 6 + m;
        const bool xok = (unsigned)xg < (unsigned)WW;
        float s1 = 0.0f;
        #pragma unroll
        for (int k = 0; k < KD; ++k) {
            const int c = k / 13, dy = k - c*13;   // compile-time
            const int y = h - 6 + dy;
            float v = 0.0f;
            if (xok && (unsigned)y < (unsigned)HH) v = limg[(c*HH + y)*WW + xg];
            s1 += v;
            Ls[k][m] = v;
        }
        colL[m] = s1;
    } else if (tid < TX + TU) {
        const int m  = tid - TX;
        const int xg = ulo - 6 + m;
        const bool xok = (unsigned)xg < (unsigned)WW;
        float s1 = 0.0f, s2 = 0.0f;
        #pragma unroll
        for (int k = 0; k < KD; ++k) {
            const int c = k / 13, dy = k - c*13;
            const int y = h - 6 + dy;
            float v = 0.0f;
            if (xok && (unsigned)y < (unsigned)HH) v = rimg[(c*HH + y)*WW + xg];
            s1 += v;
            s2 = fmaf(v, v, s2);
            Rs[k][m] = v;
        }
        if (m < TUW) {
            colR1[m] = s1;
            colR2[m] = s2;
        }
    }
    __syncthreads();                    // B0: slabs + column sums ready

    // ---- per-lane left stats ----
    float muL;
    {
        float s = 0.0f;
        #pragma unroll
        for (int dx = 0; dx < 13; ++dx) s += colL[lane + dx];
        muL = s / DTOT;
    }

    // ---- Phase A: 19x10 tiles of 4x8 (threads 0..189), packed-dual FMA;
    //      wave-3 tail (192..255) computes per-v stats from colR ----
    if (tid < 190) {
        const int ti = tid % 19, tj = tid / 19;
        const int i0 = ti * 4, j0 = tj * 8;
        v2f acc[4][4];
        #pragma unroll
        for (int r = 0; r < 4; ++r)
            #pragma unroll
            for (int c2 = 0; c2 < 4; ++c2) acc[r][c2] = (v2f){0.0f, 0.0f};
        __builtin_amdgcn_s_setprio(1);
        for (int k = 0; k < KD; ++k) {
            float4 la = *(const float4*)&Ls[k][i0];
            float4 r0 = *(const float4*)&Rs[k][j0];
            float4 r1 = *(const float4*)&Rs[k][j0+4];
            v2f rp0 = {r0.x, r0.y}, rp1 = {r0.z, r0.w};
            v2f rp2 = {r1.x, r1.y}, rp3 = {r1.z, r1.w};
            float lx[4] = {la.x, la.y, la.z, la.w};
            #pragma unroll
            for (int r = 0; r < 4; ++r) {
                v2f lb = {lx[r], lx[r]};
                acc[r][0] = __builtin_elementwise_fma(lb, rp0, acc[r][0]);
                acc[r][1] = __builtin_elementwise_fma(lb, rp1, acc[r][1]);
                acc[r][2] = __builtin_elementwise_fma(lb, rp2, acc[r][2]);
                acc[r][3] = __builtin_elementwise_fma(lb, rp3, acc[r][3]);
            }
        }
        __builtin_amdgcn_s_setprio(0);
        // transposed store: per output column j0+c, rows i0..i0+3 contiguous (col-major)
        #pragma unroll
        for (int c = 0; c < 8; ++c) {
            float4 wv = make_float4(acc[0][c>>1][c&1], acc[1][c>>1][c&1],
                                    acc[2][c>>1][c&1], acc[3][c>>1][c&1]);
            *(float4*)&Tc[j0+c][i0] = wv;
        }
    } else if (tid >= 192) {
        int vcc = tid - 192;            // 0..63
        float s1 = 0.0f, s2 = 0.0f;
        #pragma unroll
        for (int dx = 0; dx < 13; ++dx) { s1 += colR1[vcc + dx]; s2 += colR2[vcc + dx]; }
        float mu = s1 / DTOT;
        float var = fmaxf(s2 - s1*s1/DTOT, 0.0f);
        smuR[vcc] = mu;
        sivR[vcc] = 1.0f / (sqrtf(var) + 1e-5f);
    }
    __syncthreads();                    // B1: Tc + stats ready

    // ---- Phase B: diagonal 13-box sums; lane = w, wave covers 16 v's ----
    float best = -1e30f;
    int bestv = 0;
    const float dml = DTOT * muL;
    for (int vi = 0; vi < 16; ++vi) {
        int vc = wave * 16 + vi;
        const float* tp0 = &Tc[vc][0] + lane;
        float S = 0.0f;
        int boff = 0;
        #pragma unroll
        for (int g = 0; g < 3; ++g) {
            asm volatile("" : "+v"(boff));   // opaque base -> read2-pairable 0/77/154/231
            float y0 = tp0[boff];
            float y1 = tp0[boff + TD2];
            float y2 = tp0[boff + 2*TD2];
            float y3 = tp0[boff + 3*TD2];
            S += y0; S += y1; S += y2; S += y3;
            boff += 4*TD2;
        }
        S += tp0[12*TD2];
        float score = (S - dml * smuR[vc]) * sivR[vc];
        int v = ulo + vc;
        if (score > best) { best = score; bestv = v; }
    }

    // ---- merge the 4 waves' candidates per w (tie -> lower v) ----
    redS[wave][lane] = best;
    redV[wave][lane] = bestv;
    __syncthreads();
    if (tid < XS) {
        float b = redS[0][tid]; int bv = redV[0][tid];
        for (int wv = 1; wv < 4; ++wv) {
            float s = redS[wv][tid]; int v2 = redV[wv][tid];
            if (s > b || (s == b && v2 < bv)) { b = s; bv = v2; }
        }
        // order-preserving float encode; tie -> larger ~v -> lower v wins (matches jnp.argmax)
        unsigned ob = __float_as_uint(b);
        ob = (ob & 0x80000000u) ? ~ob : (ob | 0x80000000u);
        unsigned long long key = ((unsigned long long)ob << 32) | (unsigned)(~(unsigned)bv);
        if (mode) {
            sink[(size_t)ch * NPIX + h*WW + wlo + tid] = key;   // plain per-chunk store
        } else {
            atomicMax(&sink[h*WW + wlo + tid], key);
        }
    }
}

// ---------------- epilogue: keys/planes -> depth ----------------
__global__ __launch_bounds__(256) void depth_kernel(const unsigned long long* __restrict__ sink,
                                                    const float* __restrict__ sc,
                                                    float* __restrict__ out, int mode) {
    int t = blockIdx.x * 256 + threadIdx.x;   // grid sized exactly NPIX/256
    unsigned long long k = sink[t];
    if (mode) {
        #pragma unroll
        for (int p = 1; p < NCHUNK; ++p) {
            unsigned long long k2 = sink[(size_t)p * NPIX + t];
            if (k2 > k) k = k2;               // encoding: max = best score, tie -> lower v
        }
    }
    int v = (int)(~(unsigned int)k);
    float w = (float)(t % WW);
    float disp = fmaxf(fabsf((float)v - w), 0.001f);
    out[t] = sc[0] / disp;
}

// ---------------- fallback (original verified kernel) if workspace too small ----------------
__global__ __launch_bounds__(256) void match_fallback(
        const float* __restrict__ limg, const float* __restrict__ rimg,
        const float* __restrict__ ws, float* __restrict__ out) {
    __shared__ float Ls[KD][76];
    __shared__ float Rs[KD][76];
    __shared__ float Tt[76][81];
    __shared__ float colL[76];
    __shared__ float colR1[76];
    __shared__ float colR2[76];
    __shared__ float smuR[64];
    __shared__ float sivR[64];
    __shared__ float redS[4][64];
    __shared__ int   redV[4][64];

    const int span = blockIdx.x;
    const int h    = blockIdx.y;
    const int wlo  = span * 64;
    const int tid  = threadIdx.x;
    const int lane = tid & 63;
    const int wave = tid >> 6;

    for (int i = tid; i < KD*76; i += 256) {
        int k = i / 76, xl = i % 76;
        int c = k / 13, dy = k % 13;
        int y = h - 6 + dy, x = wlo - 6 + xl;
        float v = 0.0f;
        if (y >= 0 && y < HH && x >= 0 && x < WW) v = limg[(c*HH + y)*WW + x];
        Ls[k][xl] = v;
    }
    __syncthreads();

    if (tid < 76) {
        float s = 0.0f;
        for (int k = 0; k < KD; ++k) s += Ls[k][tid];
        colL[tid] = s;
    }
    __syncthreads();

    float muL;
    {
        float s = 0.0f;
        #pragma unroll
        for (int dx = 0; dx < 13; ++dx) s += colL[lane + dx];
        muL = s / DTOT;
    }

    float best = -1e30f;
    int bestv = 0;

    for (int ch = 0; ch < NCHUNK; ++ch) {
        const int ulo = ch * 64;
        for (int i = tid; i < KD*76; i += 256) {
            int k = i / 76, uc = i % 76;
            int c = k / 13, dy = k % 13;
            int y = h - 6 + dy, u = ulo - 6 + uc;
            float v = 0.0f;
            if (y >= 0 && y < HH && u >= 0 && u < WW) v = rimg[(c*HH + y)*WW + u];
            Rs[k][uc] = v;
        }
        __syncthreads();

        if (tid < 76) {
            float s1 = 0.0f, s2 = 0.0f;
            for (int k = 0; k < KD; ++k) {
                float v = Rs[k][tid];
                s1 += v;
                s2 = fmaf(v, v, s2);
            }
            colR1[tid] = s1;
            colR2[tid] = s2;
        }

        for (int t = tid; t < 361; t += 256) {
            int ti = t % 19, tj = t / 19;
            int i0 = ti * 4, j0 = tj * 4;
            float a00=0,a01=0,a02=0,a03=0, a10=0,a11=0,a12=0,a13=0;
            float a20=0,a21=0,a22=0,a23=0, a30=0,a31=0,a32=0,a33=0;
            for (int k = 0; k < KD; ++k) {
                float4 la = *(const float4*)&Ls[k][i0];
                float4 rb = *(const float4*)&Rs[k][j0];
                a00 = fmaf(la.x, rb.x, a00); a01 = fmaf(la.x, rb.y, a01);
                a02 = fmaf(la.x, rb.z, a02); a03 = fmaf(la.x, rb.w, a03);
                a10 = fmaf(la.y, rb.x, a10); a11 = fmaf(la.y, rb.y, a11);
                a12 = fmaf(la.y, rb.z, a12); a13 = fmaf(la.y, rb.w, a13);
                a20 = fmaf(la.z, rb.x, a20); a21 = fmaf(la.z, rb.y, a21);
                a22 = fmaf(la.z, rb.z, a22); a23 = fmaf(la.z, rb.w, a23);
                a30 = fmaf(la.w, rb.x, a30); a31 = fmaf(la.w, rb.y, a31);
                a32 = fmaf(la.w, rb.z, a32); a33 = fmaf(la.w, rb.w, a33);
            }
            float* tr0 = &Tt[i0+0][j0]; tr0[0]=a00; tr0[1]=a01; tr0[2]=a02; tr0[3]=a03;
            float* tr1 = &Tt[i0+1][j0]; tr1[0]=a10; tr1[1]=a11; tr1[2]=a12; tr1[3]=a13;
            float* tr2 = &Tt[i0+2][j0]; tr2[0]=a20; tr2[1]=a21; tr2[2]=a22; tr2[3]=a23;
            float* tr3 = &Tt[i0+3][j0]; tr3[0]=a30; tr3[1]=a31; tr3[2]=a32; tr3[3]=a33;
        }
        __syncthreads();

        if (tid < 64) {
            float s1 = 0.0f, s2 = 0.0f;
            #pragma unroll
            for (int dx = 0; dx < 13; ++dx) { s1 += colR1[tid + dx]; s2 += colR2[tid + dx]; }
            float mu = s1 / DTOT;
            float var = fmaxf(s2 - s1*s1/DTOT, 0.0f);
            smuR[tid] = mu;
            sivR[tid] = 1.0f / (sqrtf(var) + 1e-5f);
        }
        __syncthreads();

        for (int vi = 0; vi < 16; ++vi) {
            int vc = wave * 16 + vi;
            int v  = ulo + vc;
            const float* tp = &Tt[lane][vc];
            float S = 0.0f;
            #pragma unroll
            for (int dxp = 0; dxp < 13; ++dxp)
                S += tp[dxp * 82];
            float score = (S - DTOT * muL * smuR[vc]) * sivR[vc];
            if (score > best) { best = score; bestv = v; }
        }
    }

    redS[wave][lane] = best;
    redV[wave][lane] = bestv;
    __syncthreads();
    if (tid < 64) {
        float b = redS[0][tid]; int bv = redV[0][tid];
        for (int wv = 1; wv < 4; ++wv) {
            float s = redS[wv][tid]; int v2 = redV[wv][tid];
            if (s > b || (s == b && v2 < bv)) { b = s; bv = v2; }
        }
        int w = wlo + tid;
        float disp = fabsf((float)bv - (float)w);
        disp = fmaxf(disp, 0.001f);
        out[h*WW + w] = ws[0] / disp;
    }
}

extern "C" void kernel_launch(void* const* d_in, const int* in_sizes, int n_in,
                              void* d_out, int out_size, void* d_ws, size_t ws_size,
                              hipStream_t stream) {
    const float* limg   = (const float*)d_in[0];
    const float* rimg   = (const float*)d_in[1];
    const float* lintri = (const float*)d_in[2];
    const float* lex    = (const float*)d_in[4];
    const float* rex    = (const float*)d_in[5];
    float* out = (float*)d_out;
    float* scp = (float*)d_ws;

    const size_t needA = 8 + (size_t)NCHUNK * NPIX * 8;  // scale + 5 chunk planes
    const size_t needB = 8 + (size_t)NPIX * 8;           // scale + keys
    if (ws_size >= needA) {
        unsigned long long* planes = (unsigned long long*)d_ws + 1;
        hipLaunchKernelGGL(prep_kernel, dim3(1), dim3(64), 0, stream,
                           lintri, lex, rex, scp, (unsigned long long*)nullptr);
        hipLaunchKernelGGL(match_kernel, dim3(NSPAN, HH, NCHUNK), dim3(256), 0, stream,
                           limg, rimg, planes, 1);
        hipLaunchKernelGGL(depth_kernel, dim3(NPIX/256), dim3(256), 0, stream,
                           planes, scp, out, 1);
    } else if (ws_size >= needB) {
        unsigned long long* keys = (unsigned long long*)d_ws + 1;
        hipLaunchKernelGGL(prep_kernel, dim3(NPIX/256), dim3(256), 0, stream,
                           lintri, lex, rex, scp, keys);
        hipLaunchKernelGGL(match_kernel, dim3(NSPAN, HH, NCHUNK), dim3(256), 0, stream,
                           limg, rimg, keys, 0);
        hipLaunchKernelGGL(depth_kernel, dim3(NPIX/256), dim3(256), 0, stream,
                           keys, scp, out, 0);
    } else {
        hipLaunchKernelGGL(prep_kernel, dim3(1), dim3(64), 0, stream,
                           lintri, lex, rex, scp, (unsigned long long*)nullptr);
        hipLaunchKernelGGL(match_fallback, dim3(NSPAN, HH), dim3(256), 0, stream,
                           limg, rimg, scp, out);
    }
}

// Round 10
// 131.371 us; speedup vs baseline: 1.4836x; 1.4836x over previous
//
#include <hip/hip_runtime.h>
#include <math.h>

#define HH 192
#define WW 320
#define DTOT 507.0f
#define KD 39      // 3 channels * 13 dy
#define NSPAN 5
#define NCHUNK 5
#define XS 64      // w-span per block
#define TV 64      // v-chunk per block
#define TX 76      // XS + 12 halo (w side, "i")
#define TU 80      // TV + 12 halo padded to 80 (v side, "j")
#define TUW 76     // valid stat columns
#define TIS 76     // Tc inner (i) stride
#define TD2 77     // diagonal step in dwords (TIS+1)
#define NPIX (HH*WW)

typedef float v2f __attribute__((ext_vector_type(2)));

// ---------------- prep: scale = fx * ||(r_extri @ inv(l_extri))[:3,3]|| ; optional key zero ----------------
__global__ void prep_kernel(const float* __restrict__ li, const float* __restrict__ le,
                            const float* __restrict__ re, float* __restrict__ sc,
                            unsigned long long* __restrict__ keys) {
    int t = blockIdx.x * blockDim.x + threadIdx.x;
    if (keys != nullptr && t < NPIX) keys[t] = 0ull;
    if (t == 0) {
        float a[4][4], inv[4][4];
        for (int i = 0; i < 4; ++i)
            for (int j = 0; j < 4; ++j) { a[i][j] = le[i*4+j]; inv[i][j] = (i == j) ? 1.0f : 0.0f; }
        for (int c = 0; c < 4; ++c) {
            int p = c; float mx = fabsf(a[c][c]);
            for (int r = c+1; r < 4; ++r) { float v = fabsf(a[r][c]); if (v > mx) { mx = v; p = r; } }
            if (p != c) for (int j = 0; j < 4; ++j) {
                float tq = a[c][j]; a[c][j] = a[p][j]; a[p][j] = tq;
                tq = inv[c][j]; inv[c][j] = inv[p][j]; inv[p][j] = tq;
            }
            float id = 1.0f / a[c][c];
            for (int j = 0; j < 4; ++j) { a[c][j] *= id; inv[c][j] *= id; }
            for (int r = 0; r < 4; ++r) if (r != c) {
                float f = a[r][c];
                for (int j = 0; j < 4; ++j) { a[r][j] -= f*a[c][j]; inv[r][j] -= f*inv[c][j]; }
            }
        }
        float rel[3];
        for (int i = 0; i < 3; ++i)
            rel[i] = re[i*4+0]*inv[0][3] + re[i*4+1]*inv[1][3] + re[i*4+2]*inv[2][3] + re[i*4+3]*inv[3][3];
        float baseline = sqrtf(rel[0]*rel[0] + rel[1]*rel[1] + rel[2]*rel[2]);
        sc[0] = li[0] * baseline;
    }
}

// ---------------- match: round-6 base; colsums merged into wave 3 under Phase A, NO setprio ----------------
// Round-9 lesson: stage wide/independent (256-thread float2), never attach an ordered
// reduction to the load stream. Round-5 lesson: setprio'd GEMM waves starve a prio-0
// worker wave -> this round drops setprio (m190: ~0 for lockstep GEMM) and merges the
// colsum phase into wave 3 under Phase A with fair arbitration. All FP orders identical
// to round 6 -> absmax 0.0. Tc[j][i] col-major stride 76 (Phase-B lane-coeff 1 =
// conflict-free; diag step 77, read2-pairable offsets {0,77,154,231}). 3 barriers.
__global__ __launch_bounds__(256) void match_kernel(
        const float* __restrict__ limg, const float* __restrict__ rimg,
        unsigned long long* __restrict__ sink, int mode) {
    __shared__ float Ls[KD][TX];        // left slab: 39 x 76
    __shared__ float Rs[KD][TU];        // right slab: 39 x 80 (cols 76..79 extra, unused for stats)
    __shared__ float Tc[TU][TIS];       // column-dot tile, [j][i], stride 76
    __shared__ float colL[TX];
    __shared__ float colR1[TUW];
    __shared__ float colR2[TUW];
    __shared__ float smuR[TV];
    __shared__ float sivR[TV];
    __shared__ float redS[4][XS];
    __shared__ int   redV[4][XS];

    const int span = blockIdx.x;        // 0..4
    const int h    = blockIdx.y;        // 0..191
    const int ch   = blockIdx.z;        // 0..4
    const int wlo  = span * XS;
    const int ulo  = ch * TV;
    const int tid  = threadIdx.x;
    const int lane = tid & 63;
    const int wave = tid >> 6;

    // ---- stage left slab as float2 pairs (wlo even -> x0 even -> 8B aligned) ----
    for (int i2 = tid; i2 < KD*38; i2 += 256) {
        int k = i2 / 38, q = i2 - k*38;
        int c = k / 13, dy = k - c*13;
        int y = h - 6 + dy, x0 = wlo - 6 + 2*q;
        float2 v = make_float2(0.0f, 0.0f);
        if ((unsigned)y < (unsigned)HH) {
            const float* row = &limg[(c*HH + y)*WW];
            if ((unsigned)x0 < (unsigned)(WW-1)) {
                v = *(const float2*)&row[x0];
            } else {
                if ((unsigned)x0 < (unsigned)WW) v.x = row[x0];
                if ((unsigned)(x0+1) < (unsigned)WW) v.y = row[x0+1];
            }
        }
        *(float2*)&Ls[k][2*q] = v;
    }
    // ---- stage right slab as float2 pairs (ulo even) ----
    for (int i2 = tid; i2 < KD*40; i2 += 256) {
        int k = i2 / 40, q = i2 - k*40;
        int c = k / 13, dy = k - c*13;
        int y = h - 6 + dy, u0 = ulo - 6 + 2*q;
        float2 v = make_float2(0.0f, 0.0f);
        if ((unsigned)y < (unsigned)HH) {
            const float* row = &rimg[(c*HH + y)*WW];
            if ((unsigned)u0 < (unsigned)(WW-1)) {
                v = *(const float2*)&row[u0];
            } else {
                if ((unsigned)u0 < (unsigned)WW) v.x = row[u0];
                if ((unsigned)(u0+1) < (unsigned)WW) v.y = row[u0+1];
            }
        }
        *(float2*)&Rs[k][2*q] = v;
    }
    __syncthreads();                    // B0: slabs ready

    // ---- Phase A: waves 0-2 (threads 0..189) GEMM; wave 3 colL + colR + stats ----
    if (tid < 190) {
        const int ti = tid % 19, tj = tid / 19;
        const int i0 = ti * 4, j0 = tj * 8;
        v2f acc[4][4];
        #pragma unroll
        for (int r = 0; r < 4; ++r)
            #pragma unroll
            for (int c2 = 0; c2 < 4; ++c2) acc[r][c2] = (v2f){0.0f, 0.0f};
        for (int k = 0; k < KD; ++k) {
            float4 la = *(const float4*)&Ls[k][i0];
            float4 r0 = *(const float4*)&Rs[k][j0];
            float4 r1 = *(const float4*)&Rs[k][j0+4];
            v2f rp0 = {r0.x, r0.y}, rp1 = {r0.z, r0.w};
            v2f rp2 = {r1.x, r1.y}, rp3 = {r1.z, r1.w};
            float lx[4] = {la.x, la.y, la.z, la.w};
            #pragma unroll
            for (int r = 0; r < 4; ++r) {
                v2f lb = {lx[r], lx[r]};
                acc[r][0] = __builtin_elementwise_fma(lb, rp0, acc[r][0]);
                acc[r][1] = __builtin_elementwise_fma(lb, rp1, acc[r][1]);
                acc[r][2] = __builtin_elementwise_fma(lb, rp2, acc[r][2]);
                acc[r][3] = __builtin_elementwise_fma(lb, rp3, acc[r][3]);
            }
        }
        // transposed store: per output column j0+c, rows i0..i0+3 contiguous (col-major)
        #pragma unroll
        for (int c = 0; c < 8; ++c) {
            float4 wv = make_float4(acc[0][c>>1][c&1], acc[1][c>>1][c&1],
                                    acc[2][c>>1][c&1], acc[3][c>>1][c&1]);
            *(float4*)&Tc[j0+c][i0] = wv;
        }
    } else if (wave == 3) {
        // colL (76 cols, two strided passes) — identical k-ascending order (bit-exact)
        for (int c = lane; c < TX; c += 64) {
            float s = 0.0f;
            for (int k = 0; k < KD; ++k) s += Ls[k][c];
            colL[c] = s;
        }
        // colR sums and squares (76 cols)
        for (int c = lane; c < TUW; c += 64) {
            float s1 = 0.0f, s2 = 0.0f;
            for (int k = 0; k < KD; ++k) {
                float v = Rs[k][c];
                s1 += v;
                s2 = fmaf(v, v, s2);
            }
            colR1[c] = s1;
            colR2[c] = s2;
        }
        asm volatile("s_waitcnt lgkmcnt(0)" ::: "memory");   // wave-local: colR writes done
        {
            float s1 = 0.0f, s2 = 0.0f;
            #pragma unroll
            for (int dx = 0; dx < 13; ++dx) { s1 += colR1[lane + dx]; s2 += colR2[lane + dx]; }
            float mu = s1 / DTOT;
            float var = fmaxf(s2 - s1*s1/DTOT, 0.0f);
            smuR[lane] = mu;
            sivR[lane] = 1.0f / (sqrtf(var) + 1e-5f);
        }
    }
    __syncthreads();                    // B1: Tc + colL + stats ready

    // ---- per-lane left stats (moved post-barrier; same 13-tap ascending order) ----
    float muL;
    {
        float s = 0.0f;
        #pragma unroll
        for (int dx = 0; dx < 13; ++dx) s += colL[lane + dx];
        muL = s / DTOT;
    }
    const float dml = DTOT * muL;

    // ---- Phase B: diagonal 13-box sums; lane = w, wave covers 16 v's ----
    float best = -1e30f;
    int bestv = 0;
    for (int vi = 0; vi < 16; ++vi) {
        int vc = wave * 16 + vi;
        const float* tp0 = &Tc[vc][0] + lane;
        float S = 0.0f;
        int boff = 0;
        #pragma unroll
        for (int g = 0; g < 3; ++g) {
            asm volatile("" : "+v"(boff));   // opaque base -> read2-pairable 0/77/154/231
            float y0 = tp0[boff];
            float y1 = tp0[boff + TD2];
            float y2 = tp0[boff + 2*TD2];
            float y3 = tp0[boff + 3*TD2];
            S += y0; S += y1; S += y2; S += y3;
            boff += 4*TD2;
        }
        S += tp0[12*TD2];
        float score = (S - dml * smuR[vc]) * sivR[vc];
        int v = ulo + vc;
        if (score > best) { best = score; bestv = v; }
    }

    // ---- merge the 4 waves' candidates per w (tie -> lower v) ----
    redS[wave][lane] = best;
    redV[wave][lane] = bestv;
    __syncthreads();
    if (tid < XS) {
        float b = redS[0][tid]; int bv = redV[0][tid];
        for (int wv = 1; wv < 4; ++wv) {
            float s = redS[wv][tid]; int v2 = redV[wv][tid];
            if (s > b || (s == b && v2 < bv)) { b = s; bv = v2; }
        }
        // order-preserving float encode; tie -> larger ~v -> lower v wins (matches jnp.argmax)
        unsigned ob = __float_as_uint(b);
        ob = (ob & 0x80000000u) ? ~ob : (ob | 0x80000000u);
        unsigned long long key = ((unsigned long long)ob << 32) | (unsigned)(~(unsigned)bv);
        if (mode) {
            sink[(size_t)ch * NPIX + h*WW + wlo + tid] = key;   // plain per-chunk store
        } else {
            atomicMax(&sink[h*WW + wlo + tid], key);
        }
    }
}

// ---------------- epilogue: keys/planes -> depth ----------------
__global__ __launch_bounds__(256) void depth_kernel(const unsigned long long* __restrict__ sink,
                                                    const float* __restrict__ sc,
                                                    float* __restrict__ out, int mode) {
    int t = blockIdx.x * 256 + threadIdx.x;   // grid sized exactly NPIX/256
    unsigned long long k = sink[t];
    if (mode) {
        #pragma unroll
        for (int p = 1; p < NCHUNK; ++p) {
            unsigned long long k2 = sink[(size_t)p * NPIX + t];
            if (k2 > k) k = k2;               // encoding: max = best score, tie -> lower v
        }
    }
    int v = (int)(~(unsigned int)k);
    float w = (float)(t % WW);
    float disp = fmaxf(fabsf((float)v - w), 0.001f);
    out[t] = sc[0] / disp;
}

// ---------------- fallback (original verified kernel) if workspace too small ----------------
__global__ __launch_bounds__(256) void match_fallback(
        const float* __restrict__ limg, const float* __restrict__ rimg,
        const float* __restrict__ ws, float* __restrict__ out) {
    __shared__ float Ls[KD][76];
    __shared__ float Rs[KD][76];
    __shared__ float Tt[76][81];
    __shared__ float colL[76];
    __shared__ float colR1[76];
    __shared__ float colR2[76];
    __shared__ float smuR[64];
    __shared__ float sivR[64];
    __shared__ float redS[4][64];
    __shared__ int   redV[4][64];

    const int span = blockIdx.x;
    const int h    = blockIdx.y;
    const int wlo  = span * 64;
    const int tid  = threadIdx.x;
    const int lane = tid & 63;
    const int wave = tid >> 6;

    for (int i = tid; i < KD*76; i += 256) {
        int k = i / 76, xl = i % 76;
        int c = k / 13, dy = k % 13;
        int y = h - 6 + dy, x = wlo - 6 + xl;
        float v = 0.0f;
        if (y >= 0 && y < HH && x >= 0 && x < WW) v = limg[(c*HH + y)*WW + x];
        Ls[k][xl] = v;
    }
    __syncthreads();

    if (tid < 76) {
        float s = 0.0f;
        for (int k = 0; k < KD; ++k) s += Ls[k][tid];
        colL[tid] = s;
    }
    __syncthreads();

    float muL;
    {
        float s = 0.0f;
        #pragma unroll
        for (int dx = 0; dx < 13; ++dx) s += colL[lane + dx];
        muL = s / DTOT;
    }

    float best = -1e30f;
    int bestv = 0;

    for (int ch = 0; ch < NCHUNK; ++ch) {
        const int ulo = ch * 64;
        for (int i = tid; i < KD*76; i += 256) {
            int k = i / 76, uc = i % 76;
            int c = k / 13, dy = k % 13;
            int y = h - 6 + dy, u = ulo - 6 + uc;
            float v = 0.0f;
            if (y >= 0 && y < HH && u >= 0 && u < WW) v = rimg[(c*HH + y)*WW + u];
            Rs[k][uc] = v;
        }
        __syncthreads();

        if (tid < 76) {
            float s1 = 0.0f, s2 = 0.0f;
            for (int k = 0; k < KD; ++k) {
                float v = Rs[k][tid];
                s1 += v;
                s2 = fmaf(v, v, s2);
            }
            colR1[tid] = s1;
            colR2[tid] = s2;
        }

        for (int t = tid; t < 361; t += 256) {
            int ti = t % 19, tj = t / 19;
            int i0 = ti * 4, j0 = tj * 4;
            float a00=0,a01=0,a02=0,a03=0, a10=0,a11=0,a12=0,a13=0;
            float a20=0,a21=0,a22=0,a23=0, a30=0,a31=0,a32=0,a33=0;
            for (int k = 0; k < KD; ++k) {
                float4 la = *(const float4*)&Ls[k][i0];
                float4 rb = *(const float4*)&Rs[k][j0];
                a00 = fmaf(la.x, rb.x, a00); a01 = fmaf(la.x, rb.y, a01);
                a02 = fmaf(la.x, rb.z, a02); a03 = fmaf(la.x, rb.w, a03);
                a10 = fmaf(la.y, rb.x, a10); a11 = fmaf(la.y, rb.y, a11);
                a12 = fmaf(la.y, rb.z, a12); a13 = fmaf(la.y, rb.w, a13);
                a20 = fmaf(la.z, rb.x, a20); a21 = fmaf(la.z, rb.y, a21);
                a22 = fmaf(la.z, rb.z, a22); a23 = fmaf(la.z, rb.w, a23);
                a30 = fmaf(la.w, rb.x, a30); a31 = fmaf(la.w, rb.y, a31);
                a32 = fmaf(la.w, rb.z, a32); a33 = fmaf(la.w, rb.w, a33);
            }
            float* tr0 = &Tt[i0+0][j0]; tr0[0]=a00; tr0[1]=a01; tr0[2]=a02; tr0[3]=a03;
            float* tr1 = &Tt[i0+1][j0]; tr1[0]=a10; tr1[1]=a11; tr1[2]=a12; tr1[3]=a13;
            float* tr2 = &Tt[i0+2][j0]; tr2[0]=a20; tr2[1]=a21; tr2[2]=a22; tr2[3]=a23;
            float* tr3 = &Tt[i0+3][j0]; tr3[0]=a30; tr3[1]=a31; tr3[2]=a32; tr3[3]=a33;
        }
        __syncthreads();

        if (tid < 64) {
            float s1 = 0.0f, s2 = 0.0f;
            #pragma unroll
            for (int dx = 0; dx < 13; ++dx) { s1 += colR1[tid + dx]; s2 += colR2[tid + dx]; }
            float mu = s1 / DTOT;
            float var = fmaxf(s2 - s1*s1/DTOT, 0.0f);
            smuR[tid] = mu;
            sivR[tid] = 1.0f / (sqrtf(var) + 1e-5f);
        }
        __syncthreads();

        for (int vi = 0; vi < 16; ++vi) {
            int vc = wave * 16 + vi;
            int v  = ulo + vc;
            const float* tp = &Tt[lane][vc];
            float S = 0.0f;
            #pragma unroll
            for (int dxp = 0; dxp < 13; ++dxp)
                S += tp[dxp * 82];
            float score = (S - DTOT * muL * smuR[vc]) * sivR[vc];
            if (score > best) { best = score; bestv = v; }
        }
    }

    redS[wave][lane] = best;
    redV[wave][lane] = bestv;
    __syncthreads();
    if (tid < 64) {
        float b = redS[0][tid]; int bv = redV[0][tid];
        for (int wv = 1; wv < 4; ++wv) {
            float s = redS[wv][tid]; int v2 = redV[wv][tid];
            if (s > b || (s == b && v2 < bv)) { b = s; bv = v2; }
        }
        int w = wlo + tid;
        float disp = fabsf((float)bv - (float)w);
        disp = fmaxf(disp, 0.001f);
        out[h*WW + w] = ws[0] / disp;
    }
}

extern "C" void kernel_launch(void* const* d_in, const int* in_sizes, int n_in,
                              void* d_out, int out_size, void* d_ws, size_t ws_size,
                              hipStream_t stream) {
    const float* limg   = (const float*)d_in[0];
    const float* rimg   = (const float*)d_in[1];
    const float* lintri = (const float*)d_in[2];
    const float* lex    = (const float*)d_in[4];
    const float* rex    = (const float*)d_in[5];
    float* out = (float*)d_out;
    float* scp = (float*)d_ws;

    const size_t needA = 8 + (size_t)NCHUNK * NPIX * 8;  // scale + 5 chunk planes
    const size_t needB = 8 + (size_t)NPIX * 8;           // scale + keys
    if (ws_size >= needA) {
        unsigned long long* planes = (unsigned long long*)d_ws + 1;
        hipLaunchKernelGGL(prep_kernel, dim3(1), dim3(64), 0, stream,
                           lintri, lex, rex, scp, (unsigned long long*)nullptr);
        hipLaunchKernelGGL(match_kernel, dim3(NSPAN, HH, NCHUNK), dim3(256), 0, stream,
                           limg, rimg, planes, 1);
        hipLaunchKernelGGL(depth_kernel, dim3(NPIX/256), dim3(256), 0, stream,
                           planes, scp, out, 1);
    } else if (ws_size >= needB) {
        unsigned long long* keys = (unsigned long long*)d_ws + 1;
        hipLaunchKernelGGL(prep_kernel, dim3(NPIX/256), dim3(256), 0, stream,
                           lintri, lex, rex, scp, keys);
        hipLaunchKernelGGL(match_kernel, dim3(NSPAN, HH, NCHUNK), dim3(256), 0, stream,
                           limg, rimg, keys, 0);
        hipLaunchKernelGGL(depth_kernel, dim3(NPIX/256), dim3(256), 0, stream,
                           keys, scp, out, 0);
    } else {
        hipLaunchKernelGGL(prep_kernel, dim3(1), dim3(64), 0, stream,
                           lintri, lex, rex, scp, (unsigned long long*)nullptr);
        hipLaunchKernelGGL(match_fallback, dim3(NSPAN, HH), dim3(256), 0, stream,
                           limg, rimg, scp, out);
    }
}